// Round 4
// baseline (21.716 us; speedup 1.0000x reference)
//
#include <hip/hip_runtime.h>

// ConvQuadInterp3d: x (2,1,8,384,384) f32, hes_noise (3,3) f32
// outputs: coords_max (2,1,3,8,384,384) then y_max (2,1,8,384,384), concat flat f32.

constexpr int Dd = 8, Hh = 384, Ww = 384, BC = 2;
constexpr int HW  = Hh * Ww;          // 147456
constexpr int DHW = Dd * HW;          // 1179648
constexpr int NVOX = BC * DHW;        // 2359296
constexpr int W4 = Ww / 4;            // 96

#define BONUS_ 10.0f
#define EPS_ 1e-7f

// Load one d-plane's 3 h-rows as 6-wide w-windows [w0-1 .. w0+4] into dst[3][6]
// using replicate-clamped column offsets cm/cp; compute separable 3x3 (h,w)
// window max pmax[k] for k=0..3.
__device__ __forceinline__ void load_plane6(const float* __restrict__ pb,
                                            int ro0, int ro1, int ro2,
                                            int w0, int cm, int cp,
                                            float dst[3][6], float pmax[4]) {
    const int ro[3] = { ro0, ro1, ro2 };
    #pragma unroll
    for (int j = 0; j < 3; j++) {
        const float* row = pb + ro[j];
        float4 c4 = *(const float4*)(row + w0);
        float  em = row[cm];        // replicate-clamped w0-1
        float  ep = row[cp];        // replicate-clamped w0+4
        dst[j][0] = em;
        dst[j][1] = c4.x; dst[j][2] = c4.y; dst[j][3] = c4.z; dst[j][4] = c4.w;
        dst[j][5] = ep;
    }
    #pragma unroll
    for (int k = 0; k < 4; k++) {
        float m0 = fmaxf(fmaxf(dst[0][k], dst[0][k + 1]), dst[0][k + 2]); // v_max3
        float m1 = fmaxf(fmaxf(dst[1][k], dst[1][k + 1]), dst[1][k + 2]);
        float m2 = fmaxf(fmaxf(dst[2][k], dst[2][k + 1]), dst[2][k + 2]);
        pmax[k] = fmaxf(fmaxf(m0, m1), m2);
    }
}

__global__ __launch_bounds__(256, 4) void quad_interp3d_kernel(
    const float* __restrict__ x,
    const float* __restrict__ hn,
    float* __restrict__ out)
{
    int t = blockIdx.x * 256 + threadIdx.x;   // 0 .. 589823
    int w4 = t % W4;
    int r  = t / W4;
    int h  = r % Hh;
    int r2 = r / Hh;                           // 0..15
    int d  = r2 % Dd;
    int bc = r2 / Dd;

    const float* xb = x + bc * DHW;
    int w0 = w4 << 2;
    int cm = (w0 > 0) ? w0 - 1 : 0;            // clamped left column
    int cp = (w0 + 4 < Ww) ? w0 + 4 : Ww - 1;  // clamped right column

    int h0 = h > 0 ? h - 1 : 0;
    int h2 = h < Hh - 1 ? h + 1 : Hh - 1;
    int ro0 = h0 * Ww, ro1 = h * Ww, ro2 = h2 * Ww;

    int dm = d > 0 ? d - 1 : 0;
    int dp = d < Dd - 1 ? d + 1 : Dd - 1;

    // hoisted |hes_noise| * EPS (uniform, from kernel-arg base -> s_loads)
    float hnA[9];
    #pragma unroll
    for (int i = 0; i < 9; i++) hnA[i] = fabsf(hn[i]) * EPS_;

    float A[3][6], B[3][6], C[3][6];
    float pmA[4], pmB[4], pmC[4];
    load_plane6(xb + dm * HW, ro0, ro1, ro2, w0, cm, cp, A, pmA);
    load_plane6(xb + d  * HW, ro0, ro1, ro2, w0, cm, cp, B, pmB);
    load_plane6(xb + dp * HW, ro0, ro1, ro2, w0, cm, cp, C, pmC);

    float r0[4], r1[4], r2v[4], ry[4];
    float df = (float)d, hf = (float)h, wf = (float)w0;

    #pragma unroll
    for (int k = 0; k < 4; k++) {
        float c = B[1][k + 1];

        float mx = fmaxf(fmaxf(pmA[k], pmB[k]), pmC[k]);
        bool mask = (c == mx);

        float gx = 0.5f * (B[1][k + 2] - B[1][k]);
        float gy = 0.5f * (B[2][k + 1] - B[0][k + 1]);
        float gs = 0.5f * (C[1][k + 1] - A[1][k + 1]);

        float dxx = B[1][k + 2] - 2.f * c + B[1][k];
        float dyy = B[2][k + 1] - 2.f * c + B[0][k + 1];
        float dss = C[1][k + 1] - 2.f * c + A[1][k + 1];
        float dxy = 0.25f * (B[0][k] - B[0][k + 2] - B[2][k] + B[2][k + 2]);
        float dys = 0.25f * (A[0][k + 1] - A[2][k + 1] - C[0][k + 1] + C[2][k + 1]);
        float dxs = 0.25f * (A[1][k] - A[1][k + 2] - C[1][k] + C[1][k + 2]);

        float A00 = dxx + hnA[0];
        float A01 = dxy + hnA[1];
        float A02 = dxs + hnA[2];
        float A10 = dxy + hnA[3];
        float A11 = dyy + hnA[4];
        float A12 = dys + hnA[5];
        float A20 = dxs + hnA[6];
        float A21 = dys + hnA[7];
        float A22 = dss + hnA[8];
        float b0 = gx, b1 = gy, b2 = gs;

        // Cramer's rule, one approximate reciprocal (v_rcp_f32, ~1ulp).
        // |dx| clipped at 0.7 and tolerance is 7.68 abs -> approx error safe.
        float c00 = A11 * A22 - A12 * A21;
        float c01 = A10 * A22 - A12 * A20;
        float c02 = A10 * A21 - A11 * A20;
        float det = A00 * c00 - A01 * c01 + A02 * c02;
        float inv = __builtin_amdgcn_rcpf(det);

        float t0 = b1 * A22 - A12 * b2;
        float t1 = A10 * b2 - b1 * A20;
        float t2 = b1 * A21 - A11 * b2;

        float s0 = (b0 * c00 - A01 * t0 + A02 * t2) * inv;
        float s1 = (A00 * t0 - b0 * c01 + A02 * t1) * inv;
        float s2 = (-A00 * t2 - A01 * t1 + b0 * c02) * inv;

        float dxv0 = mask ? -s0 : 0.f;
        float dxv1 = mask ? -s1 : 0.f;
        float dxv2 = mask ? -s2 : 0.f;
        float amax = fmaxf(fabsf(dxv0), fmaxf(fabsf(dxv1), fabsf(dxv2)));
        if (amax > 0.7f) { dxv0 = 0.f; dxv1 = 0.f; dxv2 = 0.f; }
        float dyv = 0.5f * (gx * dxv0 + gy * dxv1 + gs * dxv2);

        r0[k]  = df + dxv2;                 // channel 0: d + dx_s
        r1[k]  = hf + dxv1;                 // channel 1: h + dx_y
        r2v[k] = (wf + (float)k) + dxv0;    // channel 2: w + dx_x
        ry[k]  = c + dyv + (mask ? BONUS_ : 0.f);
    }

    float* coords = out;
    float* ymax   = out + 3 * NVOX;

    int sp = d * HW + ro1 + w0;
    int cb = bc * 3 * DHW + sp;
    int yb = bc * DHW + sp;

    *(float4*)(coords + cb)           = make_float4(r0[0], r0[1], r0[2], r0[3]);
    *(float4*)(coords + cb + DHW)     = make_float4(r1[0], r1[1], r1[2], r1[3]);
    *(float4*)(coords + cb + 2 * DHW) = make_float4(r2v[0], r2v[1], r2v[2], r2v[3]);
    *(float4*)(ymax + yb)             = make_float4(ry[0], ry[1], ry[2], ry[3]);
}

extern "C" void kernel_launch(void* const* d_in, const int* in_sizes, int n_in,
                              void* d_out, int out_size, void* d_ws, size_t ws_size,
                              hipStream_t stream) {
    const float* x  = (const float*)d_in[0];
    const float* hn = (const float*)d_in[1];
    float* out = (float*)d_out;

    int total  = BC * Dd * Hh * W4;          // 589824
    int blocks = total / 256;                // 2304
    quad_interp3d_kernel<<<blocks, 256, 0, stream>>>(x, hn, out);
}

// Round 5
// 19.851 us; speedup vs baseline: 1.0940x; 1.0940x over previous
//
#include <hip/hip_runtime.h>

// ConvQuadInterp3d: x (2,1,8,384,384) f32, hes_noise (3,3) f32
// outputs: coords_max (2,1,3,8,384,384) then y_max (2,1,8,384,384), concat flat f32.

constexpr int Dd = 8, Hh = 384, Ww = 384, BC = 2;
constexpr int HW  = Hh * Ww;          // 147456
constexpr int DHW = Dd * HW;          // 1179648
constexpr int NVOX = BC * DHW;        // 2359296
constexpr int W4 = Ww / 4;            // 96

#define BONUS_ 10.0f
#define EPS_ 1e-7f

__device__ __forceinline__ float uni(float v) {
    return __int_as_float(__builtin_amdgcn_readfirstlane(__float_as_int(v)));
}

// Pure-load: one d-plane's 3 h-rows as 6-wide windows [w0-1 .. w0+4] into dst[3][6].
__device__ __forceinline__ void load_plane6(const float* __restrict__ pb,
                                            int ro0, int ro1, int ro2,
                                            int w4, float dst[3][6]) {
    const int offm = (w4 > 0)  ? -4 : 0;
    const int offp = (w4 < 95) ?  4 : 0;
    const int ro[3] = { ro0, ro1, ro2 };
    #pragma unroll
    for (int j = 0; j < 3; j++) {
        const float* row = pb + ro[j] + (w4 << 2);
        float4 c4 = *(const float4*)(row);
        float4 m4 = *(const float4*)(row + offm);
        float4 p4 = *(const float4*)(row + offp);
        dst[j][0] = (w4 > 0)  ? m4.w : c4.x;
        dst[j][1] = c4.x; dst[j][2] = c4.y; dst[j][3] = c4.z; dst[j][4] = c4.w;
        dst[j][5] = (w4 < 95) ? p4.x : c4.w;
    }
}

// Separable 3x3 (h,w) window max for k=0..3 of one plane.
__device__ __forceinline__ void plane_max(const float dst[3][6], float pmax[4]) {
    #pragma unroll
    for (int k = 0; k < 4; k++) {
        float m0 = fmaxf(fmaxf(dst[0][k], dst[0][k + 1]), dst[0][k + 2]); // v_max3
        float m1 = fmaxf(fmaxf(dst[1][k], dst[1][k + 1]), dst[1][k + 2]);
        float m2 = fmaxf(fmaxf(dst[2][k], dst[2][k + 1]), dst[2][k + 2]);
        pmax[k] = fmaxf(fmaxf(m0, m1), m2);
    }
}

// Compute 4 voxels (one w-strip) at depth d from planes A(d-1), B(d), C(d+1); store.
__device__ __forceinline__ void compute_store(
    const float A[3][6], const float B[3][6], const float C[3][6],
    const float pmA[4], const float pmB[4], const float pmC[4],
    const float* __restrict__ hnA,     // 9 wave-uniform values: |hn[i]|*EPS
    float* __restrict__ coords, float* __restrict__ ymax,
    int d, int h, int w0, int cbase, int ybase)
{
    float r0[4], r1[4], r2[4], ry[4];

    #pragma unroll
    for (int k = 0; k < 4; k++) {
        float c = B[1][k + 1];

        float mx = fmaxf(fmaxf(pmA[k], pmB[k]), pmC[k]);
        bool mask = (c == mx);

        float gx = 0.5f * (B[1][k + 2] - B[1][k]);
        float gy = 0.5f * (B[2][k + 1] - B[0][k + 1]);
        float gs = 0.5f * (C[1][k + 1] - A[1][k + 1]);

        float dxx = B[1][k + 2] - 2.f * c + B[1][k];
        float dyy = B[2][k + 1] - 2.f * c + B[0][k + 1];
        float dss = C[1][k + 1] - 2.f * c + A[1][k + 1];
        float dxy = 0.25f * (B[0][k] - B[0][k + 2] - B[2][k] + B[2][k + 2]);
        float dys = 0.25f * (A[0][k + 1] - A[2][k + 1] - C[0][k + 1] + C[2][k + 1]);
        float dxs = 0.25f * (A[1][k] - A[1][k + 2] - C[1][k] + C[1][k + 2]);

        float A00 = dxx + hnA[0];
        float A01 = dxy + hnA[1];
        float A02 = dxs + hnA[2];
        float A10 = dxy + hnA[3];
        float A11 = dyy + hnA[4];
        float A12 = dys + hnA[5];
        float A20 = dxs + hnA[6];
        float A21 = dys + hnA[7];
        float A22 = dss + hnA[8];
        float b0 = gx, b1 = gy, b2 = gs;

        // Cramer's rule with one approximate reciprocal (v_rcp_f32, ~1ulp).
        // |dx| clipped at 0.7, tolerance 7.68 abs -> approx error safe;
        // near-singular cases clip to 0 under both LU and Cramer.
        float c00 = A11 * A22 - A12 * A21;
        float c01 = A10 * A22 - A12 * A20;
        float c02 = A10 * A21 - A11 * A20;
        float det = A00 * c00 - A01 * c01 + A02 * c02;
        float inv = __builtin_amdgcn_rcpf(det);

        float t0 = b1 * A22 - A12 * b2;
        float t1 = A10 * b2 - b1 * A20;
        float t2 = b1 * A21 - A11 * b2;

        float s0 = (b0 * c00 - A01 * t0 + A02 * t2) * inv;
        float s1 = (A00 * t0 - b0 * c01 + A02 * t1) * inv;
        float s2 = (-A00 * t2 - A01 * t1 + b0 * c02) * inv;

        float dxv0 = mask ? -s0 : 0.f;
        float dxv1 = mask ? -s1 : 0.f;
        float dxv2 = mask ? -s2 : 0.f;
        float amax = fmaxf(fabsf(dxv0), fmaxf(fabsf(dxv1), fabsf(dxv2)));
        if (amax > 0.7f) { dxv0 = 0.f; dxv1 = 0.f; dxv2 = 0.f; }
        float dyv = 0.5f * (gx * dxv0 + gy * dxv1 + gs * dxv2);

        r0[k] = (float)d + dxv2;            // channel 0: d + dx_s
        r1[k] = (float)h + dxv1;            // channel 1: h + dx_y
        r2[k] = (float)(w0 + k) + dxv0;     // channel 2: w + dx_x
        ry[k] = c + dyv + (mask ? BONUS_ : 0.f);
    }

    *(float4*)(coords + cbase)           = make_float4(r0[0], r0[1], r0[2], r0[3]);
    *(float4*)(coords + cbase + DHW)     = make_float4(r1[0], r1[1], r1[2], r1[3]);
    *(float4*)(coords + cbase + 2 * DHW) = make_float4(r2[0], r2[1], r2[2], r2[3]);
    *(float4*)(ymax + ybase)             = make_float4(ry[0], ry[1], ry[2], ry[3]);
}

__global__ __launch_bounds__(256) void quad_interp3d_kernel(
    const float* __restrict__ x,
    const float* __restrict__ hn,
    float* __restrict__ out)
{
    int t = blockIdx.x * 256 + threadIdx.x;   // 0 .. 294911
    int w4 = t % W4;
    int r  = t / W4;
    int h  = r % Hh;
    int r2 = r / Hh;
    int dt = r2 % 4;       // d-pair index: d0 = 2*dt
    int bc = r2 / 4;

    const float* xb = x + bc * DHW;
    int w0 = w4 << 2;

    int h0 = h > 0 ? h - 1 : 0;
    int h2 = h < Hh - 1 ? h + 1 : Hh - 1;
    int ro0 = h0 * Ww, ro1 = h * Ww, ro2 = h2 * Ww;

    int d0  = dt * 2;
    int pm1 = d0 > 0 ? d0 - 1 : 0;   // plane d0-1 (clamped)
    int pp1 = d0 + 1;                // <= 7
    int pp2 = d0 + 2 < Dd ? d0 + 2 : Dd - 1;

    // All 36 global loads issued before any reduction/compute.
    float P0[3][6], P1[3][6], P2[3][6], P3[3][6];
    load_plane6(xb + pm1 * HW, ro0, ro1, ro2, w4, P0);
    load_plane6(xb + d0  * HW, ro0, ro1, ro2, w4, P1);
    load_plane6(xb + pp1 * HW, ro0, ro1, ro2, w4, P2);
    load_plane6(xb + pp2 * HW, ro0, ro1, ro2, w4, P3);

    // hes_noise -> wave-uniform scalars (SGPRs)
    float hnA[9];
    #pragma unroll
    for (int i = 0; i < 9; i++) hnA[i] = uni(fabsf(hn[i]) * EPS_);

    float m0[4], m1[4], m2[4], m3[4];
    plane_max(P0, m0);
    plane_max(P1, m1);
    plane_max(P2, m2);
    plane_max(P3, m3);

    float* coords = out;
    float* ymax   = out + 3 * NVOX;

    int sp0 = d0 * HW + ro1 + w0;
    int cb  = bc * 3 * DHW + sp0;
    int yb  = bc * DHW + sp0;

    compute_store(P0, P1, P2, m0, m1, m2, hnA, coords, ymax, d0,     h, w0, cb,      yb);
    compute_store(P1, P2, P3, m1, m2, m3, hnA, coords, ymax, d0 + 1, h, w0, cb + HW, yb + HW);
}

extern "C" void kernel_launch(void* const* d_in, const int* in_sizes, int n_in,
                              void* d_out, int out_size, void* d_ws, size_t ws_size,
                              hipStream_t stream) {
    const float* x  = (const float*)d_in[0];
    const float* hn = (const float*)d_in[1];
    float* out = (float*)d_out;

    int total  = BC * 4 * Hh * W4;           // 294912
    int blocks = total / 256;                // 1152
    quad_interp3d_kernel<<<blocks, 256, 0, stream>>>(x, hn, out);
}

// Round 7
// 17.083 us; speedup vs baseline: 1.2712x; 1.1620x over previous
//
#include <hip/hip_runtime.h>

// ConvQuadInterp3d: x (2,1,8,384,384) f32, hes_noise (3,3) f32
// outputs: coords_max (2,1,3,8,384,384) then y_max (2,1,8,384,384), concat flat f32.
//
// Structure (R2-best): one thread per (d-pair, h, w-strip of 4). 4 d-planes in
// registers, separable 3x3x3 NMS max, Cramer solve with v_rcp_f32, nontemporal
// float4 stores (output is write-once; keep L2 for x).

constexpr int Dd = 8, Hh = 384, Ww = 384, BC = 2;
constexpr int HW  = Hh * Ww;          // 147456
constexpr int DHW = Dd * HW;          // 1179648
constexpr int NVOX = BC * DHW;        // 2359296
constexpr int W4 = Ww / 4;            // 96

#define BONUS_ 10.0f
#define EPS_ 1e-7f

typedef float f32x4 __attribute__((ext_vector_type(4)));

__device__ __forceinline__ float uni(float v) {
    return __int_as_float(__builtin_amdgcn_readfirstlane(__float_as_int(v)));
}

__device__ __forceinline__ void nt_store4(float* p, float a, float b, float c, float d) {
    f32x4 v = { a, b, c, d };
    __builtin_nontemporal_store(v, (f32x4*)p);
}

// Load one d-plane's 3 h-rows as 6-wide w-windows [w0-1 .. w0+4] into dst[3][6],
// and compute the separable 3x3 (h,w) window max pmax[k] for k=0..3.
__device__ __forceinline__ void load_plane6(const float* __restrict__ pb,
                                            int ro0, int ro1, int ro2,
                                            int w4, float dst[3][6], float pmax[4]) {
    const int offm = (w4 > 0)  ? -4 : 0;
    const int offp = (w4 < 95) ?  4 : 0;
    const int ro[3] = { ro0, ro1, ro2 };
    #pragma unroll
    for (int j = 0; j < 3; j++) {
        const float* row = pb + ro[j] + (w4 << 2);
        float4 c4 = *(const float4*)(row);
        float4 m4 = *(const float4*)(row + offm);
        float4 p4 = *(const float4*)(row + offp);
        dst[j][0] = (w4 > 0)  ? m4.w : c4.x;
        dst[j][1] = c4.x; dst[j][2] = c4.y; dst[j][3] = c4.z; dst[j][4] = c4.w;
        dst[j][5] = (w4 < 95) ? p4.x : c4.w;
    }
    #pragma unroll
    for (int k = 0; k < 4; k++) {
        float m0 = fmaxf(fmaxf(dst[0][k], dst[0][k + 1]), dst[0][k + 2]); // v_max3
        float m1 = fmaxf(fmaxf(dst[1][k], dst[1][k + 1]), dst[1][k + 2]);
        float m2 = fmaxf(fmaxf(dst[2][k], dst[2][k + 1]), dst[2][k + 2]);
        pmax[k] = fmaxf(fmaxf(m0, m1), m2);
    }
}

// Compute 4 voxels (one w-strip) at depth d from planes A(d-1), B(d), C(d+1); store.
__device__ __forceinline__ void compute_store(
    const float A[3][6], const float B[3][6], const float C[3][6],
    const float pmA[4], const float pmB[4], const float pmC[4],
    const float* __restrict__ hnA,     // 9 wave-uniform values: |hn[i]|*EPS
    float* __restrict__ coords, float* __restrict__ ymax,
    int d, int h, int w0, int cbase, int ybase)
{
    float r0[4], r1[4], r2[4], ry[4];

    #pragma unroll
    for (int k = 0; k < 4; k++) {
        float c = B[1][k + 1];

        float mx = fmaxf(fmaxf(pmA[k], pmB[k]), pmC[k]);
        bool mask = (c == mx);

        float gx = 0.5f * (B[1][k + 2] - B[1][k]);
        float gy = 0.5f * (B[2][k + 1] - B[0][k + 1]);
        float gs = 0.5f * (C[1][k + 1] - A[1][k + 1]);

        float dxx = B[1][k + 2] - 2.f * c + B[1][k];
        float dyy = B[2][k + 1] - 2.f * c + B[0][k + 1];
        float dss = C[1][k + 1] - 2.f * c + A[1][k + 1];
        float dxy = 0.25f * (B[0][k] - B[0][k + 2] - B[2][k] + B[2][k + 2]);
        float dys = 0.25f * (A[0][k + 1] - A[2][k + 1] - C[0][k + 1] + C[2][k + 1]);
        float dxs = 0.25f * (A[1][k] - A[1][k + 2] - C[1][k] + C[1][k + 2]);

        float A00 = dxx + hnA[0];
        float A01 = dxy + hnA[1];
        float A02 = dxs + hnA[2];
        float A10 = dxy + hnA[3];
        float A11 = dyy + hnA[4];
        float A12 = dys + hnA[5];
        float A20 = dxs + hnA[6];
        float A21 = dys + hnA[7];
        float A22 = dss + hnA[8];
        float b0 = gx, b1 = gy, b2 = gs;

        // Cramer's rule with one approximate reciprocal (v_rcp_f32, ~1ulp).
        // |dx| clipped at 0.7, tolerance 7.68 abs -> approx error safe;
        // near-singular cases clip to 0 under both LU and Cramer.
        float c00 = A11 * A22 - A12 * A21;
        float c01 = A10 * A22 - A12 * A20;
        float c02 = A10 * A21 - A11 * A20;
        float det = A00 * c00 - A01 * c01 + A02 * c02;
        float inv = __builtin_amdgcn_rcpf(det);

        float t0 = b1 * A22 - A12 * b2;
        float t1 = A10 * b2 - b1 * A20;
        float t2 = b1 * A21 - A11 * b2;

        float s0 = (b0 * c00 - A01 * t0 + A02 * t2) * inv;
        float s1 = (A00 * t0 - b0 * c01 + A02 * t1) * inv;
        float s2 = (-A00 * t2 - A01 * t1 + b0 * c02) * inv;

        float dxv0 = mask ? -s0 : 0.f;
        float dxv1 = mask ? -s1 : 0.f;
        float dxv2 = mask ? -s2 : 0.f;
        float amax = fmaxf(fabsf(dxv0), fmaxf(fabsf(dxv1), fabsf(dxv2)));
        if (amax > 0.7f) { dxv0 = 0.f; dxv1 = 0.f; dxv2 = 0.f; }
        float dyv = 0.5f * (gx * dxv0 + gy * dxv1 + gs * dxv2);

        r0[k] = (float)d + dxv2;            // channel 0: d + dx_s
        r1[k] = (float)h + dxv1;            // channel 1: h + dx_y
        r2[k] = (float)(w0 + k) + dxv0;     // channel 2: w + dx_x
        ry[k] = c + dyv + (mask ? BONUS_ : 0.f);
    }

    // Nontemporal (streaming) stores: output is write-once, keep L2 for x.
    nt_store4(coords + cbase,           r0[0], r0[1], r0[2], r0[3]);
    nt_store4(coords + cbase + DHW,     r1[0], r1[1], r1[2], r1[3]);
    nt_store4(coords + cbase + 2 * DHW, r2[0], r2[1], r2[2], r2[3]);
    nt_store4(ymax + ybase,             ry[0], ry[1], ry[2], ry[3]);
}

__global__ __launch_bounds__(256) void quad_interp3d_kernel(
    const float* __restrict__ x,
    const float* __restrict__ hn,
    float* __restrict__ out)
{
    int t = blockIdx.x * 256 + threadIdx.x;   // 0 .. 294911
    int w4 = t % W4;
    int r  = t / W4;
    int h  = r % Hh;
    int r2 = r / Hh;
    int dt = r2 % 4;       // d-pair index: d0 = 2*dt
    int bc = r2 / 4;

    const float* xb = x + bc * DHW;
    int w0 = w4 << 2;

    int h0 = h > 0 ? h - 1 : 0;
    int h2 = h < Hh - 1 ? h + 1 : Hh - 1;
    int ro0 = h0 * Ww, ro1 = h * Ww, ro2 = h2 * Ww;

    int d0  = dt * 2;
    int pm1 = d0 > 0 ? d0 - 1 : 0;   // plane d0-1 (clamped)
    int pp1 = d0 + 1;                // <= 7
    int pp2 = d0 + 2 < Dd ? d0 + 2 : Dd - 1;

    // hes_noise -> wave-uniform scalars (SGPRs)
    float hnA[9];
    #pragma unroll
    for (int i = 0; i < 9; i++) hnA[i] = uni(fabsf(hn[i]) * EPS_);

    float P0[3][6], P1[3][6], P2[3][6], P3[3][6];
    float m0[4], m1[4], m2[4], m3[4];
    load_plane6(xb + pm1 * HW, ro0, ro1, ro2, w4, P0, m0);
    load_plane6(xb + d0  * HW, ro0, ro1, ro2, w4, P1, m1);
    load_plane6(xb + pp1 * HW, ro0, ro1, ro2, w4, P2, m2);
    load_plane6(xb + pp2 * HW, ro0, ro1, ro2, w4, P3, m3);

    float* coords = out;
    float* ymax   = out + 3 * NVOX;

    int sp0 = d0 * HW + ro1 + w0;
    int cb  = bc * 3 * DHW + sp0;
    int yb  = bc * DHW + sp0;

    compute_store(P0, P1, P2, m0, m1, m2, hnA, coords, ymax, d0,     h, w0, cb,      yb);
    compute_store(P1, P2, P3, m1, m2, m3, hnA, coords, ymax, d0 + 1, h, w0, cb + HW, yb + HW);
}

extern "C" void kernel_launch(void* const* d_in, const int* in_sizes, int n_in,
                              void* d_out, int out_size, void* d_ws, size_t ws_size,
                              hipStream_t stream) {
    const float* x  = (const float*)d_in[0];
    const float* hn = (const float*)d_in[1];
    float* out = (float*)d_out;

    int total  = BC * 4 * Hh * W4;           // 294912
    int blocks = total / 256;                // 1152
    quad_interp3d_kernel<<<blocks, 256, 0, stream>>>(x, hn, out);
}

// Round 8
// 17.065 us; speedup vs baseline: 1.2726x; 1.0010x over previous
//
#include <hip/hip_runtime.h>

// ConvQuadInterp3d: x (2,1,8,384,384) f32, hes_noise (3,3) f32
// outputs: coords_max (2,1,3,8,384,384) then y_max (2,1,8,384,384), concat flat f32.
//
// Structure: one thread per (d-pair, h, w-strip of 4). 4 d-planes in registers,
// per-row loads = 1 aligned float4 (dst[1..4]) + 2 coalesced scalar edge loads
// (dst[0], dst[5]) -> 24 TD-cycles/row vs 48 for 3x float4. Separable 3x3x3 NMS,
// Cramer solve with v_rcp_f32, nontemporal float4 stores (write-once output).

constexpr int Dd = 8, Hh = 384, Ww = 384, BC = 2;
constexpr int HW  = Hh * Ww;          // 147456
constexpr int DHW = Dd * HW;          // 1179648
constexpr int NVOX = BC * DHW;        // 2359296
constexpr int W4 = Ww / 4;            // 96

#define BONUS_ 10.0f
#define EPS_ 1e-7f

typedef float f32x4 __attribute__((ext_vector_type(4)));

__device__ __forceinline__ float uni(float v) {
    return __int_as_float(__builtin_amdgcn_readfirstlane(__float_as_int(v)));
}

__device__ __forceinline__ void nt_store4(float* p, float a, float b, float c, float d) {
    f32x4 v = { a, b, c, d };
    __builtin_nontemporal_store(v, (f32x4*)p);
}

// Load one d-plane's 3 h-rows as 6-wide w-windows [w0-1 .. w0+4] into dst[3][6],
// and compute the separable 3x3 (h,w) window max pmax[k] for k=0..3.
// Per row: one aligned float4 at w0 (dst[1..4]) + scalar loads at clamped
// columns cm=max(w0-1,0), cp=min(w0+4,383) (dst[0], dst[5]).  Replicate-exact.
__device__ __forceinline__ void load_plane6(const float* __restrict__ pb,
                                            int ro0, int ro1, int ro2,
                                            int w0, int cm, int cp,
                                            float dst[3][6], float pmax[4]) {
    const int ro[3] = { ro0, ro1, ro2 };
    #pragma unroll
    for (int j = 0; j < 3; j++) {
        const float* row = pb + ro[j];
        float4 c4 = *(const float4*)(row + w0);
        float  em = row[cm];
        float  ep = row[cp];
        dst[j][0] = em;
        dst[j][1] = c4.x; dst[j][2] = c4.y; dst[j][3] = c4.z; dst[j][4] = c4.w;
        dst[j][5] = ep;
    }
    #pragma unroll
    for (int k = 0; k < 4; k++) {
        float m0 = fmaxf(fmaxf(dst[0][k], dst[0][k + 1]), dst[0][k + 2]); // v_max3
        float m1 = fmaxf(fmaxf(dst[1][k], dst[1][k + 1]), dst[1][k + 2]);
        float m2 = fmaxf(fmaxf(dst[2][k], dst[2][k + 1]), dst[2][k + 2]);
        pmax[k] = fmaxf(fmaxf(m0, m1), m2);
    }
}

// Compute 4 voxels (one w-strip) at depth d from planes A(d-1), B(d), C(d+1); store.
__device__ __forceinline__ void compute_store(
    const float A[3][6], const float B[3][6], const float C[3][6],
    const float pmA[4], const float pmB[4], const float pmC[4],
    const float* __restrict__ hnA,     // 9 wave-uniform values: |hn[i]|*EPS
    float* __restrict__ coords, float* __restrict__ ymax,
    int d, int h, int w0, int cbase, int ybase)
{
    float r0[4], r1[4], r2[4], ry[4];

    #pragma unroll
    for (int k = 0; k < 4; k++) {
        float c = B[1][k + 1];

        float mx = fmaxf(fmaxf(pmA[k], pmB[k]), pmC[k]);
        bool mask = (c == mx);

        float gx = 0.5f * (B[1][k + 2] - B[1][k]);
        float gy = 0.5f * (B[2][k + 1] - B[0][k + 1]);
        float gs = 0.5f * (C[1][k + 1] - A[1][k + 1]);

        float dxx = B[1][k + 2] - 2.f * c + B[1][k];
        float dyy = B[2][k + 1] - 2.f * c + B[0][k + 1];
        float dss = C[1][k + 1] - 2.f * c + A[1][k + 1];
        float dxy = 0.25f * (B[0][k] - B[0][k + 2] - B[2][k] + B[2][k + 2]);
        float dys = 0.25f * (A[0][k + 1] - A[2][k + 1] - C[0][k + 1] + C[2][k + 1]);
        float dxs = 0.25f * (A[1][k] - A[1][k + 2] - C[1][k] + C[1][k + 2]);

        float A00 = dxx + hnA[0];
        float A01 = dxy + hnA[1];
        float A02 = dxs + hnA[2];
        float A10 = dxy + hnA[3];
        float A11 = dyy + hnA[4];
        float A12 = dys + hnA[5];
        float A20 = dxs + hnA[6];
        float A21 = dys + hnA[7];
        float A22 = dss + hnA[8];
        float b0 = gx, b1 = gy, b2 = gs;

        // Cramer's rule with one approximate reciprocal (v_rcp_f32, ~1ulp).
        // |dx| clipped at 0.7, tolerance 7.68 abs -> approx error safe;
        // near-singular cases clip to 0 under both LU and Cramer.
        float c00 = A11 * A22 - A12 * A21;
        float c01 = A10 * A22 - A12 * A20;
        float c02 = A10 * A21 - A11 * A20;
        float det = A00 * c00 - A01 * c01 + A02 * c02;
        float inv = __builtin_amdgcn_rcpf(det);

        float t0 = b1 * A22 - A12 * b2;
        float t1 = A10 * b2 - b1 * A20;
        float t2 = b1 * A21 - A11 * b2;

        float s0 = (b0 * c00 - A01 * t0 + A02 * t2) * inv;
        float s1 = (A00 * t0 - b0 * c01 + A02 * t1) * inv;
        float s2 = (-A00 * t2 - A01 * t1 + b0 * c02) * inv;

        float dxv0 = mask ? -s0 : 0.f;
        float dxv1 = mask ? -s1 : 0.f;
        float dxv2 = mask ? -s2 : 0.f;
        float amax = fmaxf(fabsf(dxv0), fmaxf(fabsf(dxv1), fabsf(dxv2)));
        if (amax > 0.7f) { dxv0 = 0.f; dxv1 = 0.f; dxv2 = 0.f; }
        float dyv = 0.5f * (gx * dxv0 + gy * dxv1 + gs * dxv2);

        r0[k] = (float)d + dxv2;            // channel 0: d + dx_s
        r1[k] = (float)h + dxv1;            // channel 1: h + dx_y
        r2[k] = (float)(w0 + k) + dxv0;     // channel 2: w + dx_x
        ry[k] = c + dyv + (mask ? BONUS_ : 0.f);
    }

    // Nontemporal (streaming) stores: output is write-once, keep L2 for x.
    nt_store4(coords + cbase,           r0[0], r0[1], r0[2], r0[3]);
    nt_store4(coords + cbase + DHW,     r1[0], r1[1], r1[2], r1[3]);
    nt_store4(coords + cbase + 2 * DHW, r2[0], r2[1], r2[2], r2[3]);
    nt_store4(ymax + ybase,             ry[0], ry[1], ry[2], ry[3]);
}

__global__ __launch_bounds__(256) void quad_interp3d_kernel(
    const float* __restrict__ x,
    const float* __restrict__ hn,
    float* __restrict__ out)
{
    int t = blockIdx.x * 256 + threadIdx.x;   // 0 .. 294911
    int w4 = t % W4;
    int r  = t / W4;
    int h  = r % Hh;
    int r2 = r / Hh;
    int dt = r2 % 4;       // d-pair index: d0 = 2*dt
    int bc = r2 / 4;

    const float* xb = x + bc * DHW;
    int w0 = w4 << 2;
    int cm = (w0 > 0) ? w0 - 1 : 0;            // clamped left column
    int cp = (w0 + 4 < Ww) ? w0 + 4 : Ww - 1;  // clamped right column

    int h0 = h > 0 ? h - 1 : 0;
    int h2 = h < Hh - 1 ? h + 1 : Hh - 1;
    int ro0 = h0 * Ww, ro1 = h * Ww, ro2 = h2 * Ww;

    int d0  = dt * 2;
    int pm1 = d0 > 0 ? d0 - 1 : 0;   // plane d0-1 (clamped)
    int pp1 = d0 + 1;                // <= 7
    int pp2 = d0 + 2 < Dd ? d0 + 2 : Dd - 1;

    // hes_noise -> wave-uniform scalars (SGPRs)
    float hnA[9];
    #pragma unroll
    for (int i = 0; i < 9; i++) hnA[i] = uni(fabsf(hn[i]) * EPS_);

    float P0[3][6], P1[3][6], P2[3][6], P3[3][6];
    float m0[4], m1[4], m2[4], m3[4];
    load_plane6(xb + pm1 * HW, ro0, ro1, ro2, w0, cm, cp, P0, m0);
    load_plane6(xb + d0  * HW, ro0, ro1, ro2, w0, cm, cp, P1, m1);
    load_plane6(xb + pp1 * HW, ro0, ro1, ro2, w0, cm, cp, P2, m2);
    load_plane6(xb + pp2 * HW, ro0, ro1, ro2, w0, cm, cp, P3, m3);

    float* coords = out;
    float* ymax   = out + 3 * NVOX;

    int sp0 = d0 * HW + ro1 + w0;
    int cb  = bc * 3 * DHW + sp0;
    int yb  = bc * DHW + sp0;

    compute_store(P0, P1, P2, m0, m1, m2, hnA, coords, ymax, d0,     h, w0, cb,      yb);
    compute_store(P1, P2, P3, m1, m2, m3, hnA, coords, ymax, d0 + 1, h, w0, cb + HW, yb + HW);
}

extern "C" void kernel_launch(void* const* d_in, const int* in_sizes, int n_in,
                              void* d_out, int out_size, void* d_ws, size_t ws_size,
                              hipStream_t stream) {
    const float* x  = (const float*)d_in[0];
    const float* hn = (const float*)d_in[1];
    float* out = (float*)d_out;

    int total  = BC * 4 * Hh * W4;           // 294912
    int blocks = total / 256;                // 1152
    quad_interp3d_kernel<<<blocks, 256, 0, stream>>>(x, hn, out);
}